// Round 4
// baseline (394.885 us; speedup 1.0000x reference)
//
#include <hip/hip_runtime.h>

#define B_ 4096
#define T_ 32
#define A_ 4
#define OBS_ 115
#define H_ 64
#define IN_DIM_ 99
#define ACT_ 19
#define NBT (B_*T_)

typedef _Float16 f16;
typedef _Float16 f16x8 __attribute__((ext_vector_type(8)));
typedef float f32x4 __attribute__((ext_vector_type(4)));

static __device__ __forceinline__ float sigmoid_f(float x) {
    return __builtin_amdgcn_rcpf(1.f + __expf(-x));
}
static __device__ __forceinline__ float tanh_f(float x) {
    return 1.f - 2.f * __builtin_amdgcn_rcpf(1.f + __expf(2.f * x));
}
static __device__ __forceinline__ f32x4 mfma16(f16x8 a, f16x8 b, f32x4 c) {
    return __builtin_amdgcn_mfma_f32_16x16x32_f16(a, b, c, 0, 0, 0);
}

// ---------------- K0: transpose proj_W (64x99) -> WT (99x64) -----------------
__global__ __launch_bounds__(256) void k0_transpose(const float* __restrict__ W,
                                                    float* __restrict__ WT) {
    int idx = blockIdx.x * 256 + threadIdx.x;
    if (idx < IN_DIM_ * H_) {
        int i = idx >> 6, h = idx & 63;
        WT[idx] = W[h * IN_DIM_ + i];
    }
}

// ------- K1: fused feature extraction + projection + LayerNorm + ReLU --------
__global__ __launch_bounds__(256) void k1_fused(const float* __restrict__ obs,
                                                const int* __restrict__ act,
                                                const float* __restrict__ WT,
                                                const float* __restrict__ pb,
                                                const float* __restrict__ lng,
                                                const float* __restrict__ lnb,
                                                f16* __restrict__ xout) {
    __shared__ float fl[256 * 25];
    __shared__ int al[256 * 5];
    int tid = threadIdx.x;
    int n = blockIdx.x * 256 + tid;                  // bt index
    const float* o = obs + (size_t)n * (A_ * OBS_);

    float px[A_], py[A_];
#pragma unroll
    for (int a = 0; a < A_; a++) { px[a] = o[a * OBS_]; py[a] = o[a * OBS_ + 1]; }
    float bx = o[88], by = o[89];
    int t0 = n & (T_ - 1);
    float pbx = bx, pby = by;
    if (t0 > 0) { pbx = o[88 - A_ * OBS_]; pby = o[89 - A_ * OBS_]; }

    float cx = (px[0] + px[1] + px[2] + px[3]) * 0.25f;
    float cy = (py[0] + py[1] + py[2] + py[3]) * 0.25f;
    float sp = 0.f;
#pragma unroll
    for (int a = 0; a < A_; a++) { float dx = px[a] - cx, dy = py[a] - cy; sp += dx * dx + dy * dy; }
    sp = sqrtf(sp * 0.25f + 1e-6f);

    float crx[A_], cry[A_];
#pragma unroll
    for (int i = 0; i < A_; i++) {
        float best = 3.4e38f; int bj = 0;
#pragma unroll
        for (int j = 0; j < A_; j++) {
            if (j == i) continue;
            float dx = px[i] - px[j], dy = py[i] - py[j];
            float d2 = dx * dx + dy * dy;
            if (d2 < best) { best = d2; bj = j; }
        }
        crx[i] = px[bj] - px[i]; cry[i] = py[bj] - py[i];
    }

    float* f = &fl[tid * 25];
    f[0] = bx; f[1] = by; f[2] = bx - pbx; f[3] = by - pby;
#pragma unroll
    for (int a = 0; a < A_; a++) { f[4 + 2 * a] = px[a]; f[5 + 2 * a] = py[a]; }
    f[12] = cx; f[13] = cy; f[14] = sp;
#pragma unroll
    for (int a = 0; a < A_; a++) { f[15 + 2 * a] = crx[a]; f[16 + 2 * a] = cry[a]; }
#pragma unroll
    for (int a = 0; a < A_; a++) al[tid * 5 + a] = act[n * A_ + a];
    __syncthreads();

    // ---- Phase B ----
    int lane = tid & 63;
    int wv = __builtin_amdgcn_readfirstlane(tid >> 6);
    float wc[23];
#pragma unroll
    for (int i = 0; i < 23; i++) wc[i] = WT[i * 64 + lane];
    float pbv = pb[lane], g = lng[lane], bb = lnb[lane];
    int b0 = blockIdx.x * 8 + wv * 2;

    for (int it = 0; it < 64; it++) {
        int lb = wv * 64 + it;
        int b = b0 + (it >> 5);
        int t = it & 31;
        const float* fp = &fl[lb * 25];
        float v = pbv;
#pragma unroll
        for (int i = 0; i < 23; i++) v += fp[i] * wc[i];
#pragma unroll
        for (int a = 0; a < A_; a++) {
            int ai = al[lb * 5 + a];
            v += WT[(23 + a * ACT_ + ai) * 64 + lane];
        }
        float s = v, ss = v * v;
#pragma unroll
        for (int m = 1; m < 64; m <<= 1) {
            s += __shfl_xor(s, m, 64);
            ss += __shfl_xor(ss, m, 64);
        }
        float mean = s * (1.f / 64.f);
        float var = ss * (1.f / 64.f) - mean * mean;
        float xn = (v - mean) * rsqrtf(var + 1e-5f) * g + bb;
        xn = fmaxf(xn, 0.f);
        xout[((size_t)t * B_ + b) * 64 + lane] = (f16)xn;
    }
}

// ------------- K2: fused 2-layer GRU (fp16 MFMA) + classifier ----------------
// 16 batch rows per block, 512 threads = 8 waves, LAYER-SPLIT:
//   waves 0-3: layer 0, strip S=(wv&3)*16;  waves 4-7: layer 1.
// Each SIMD hosts one L0-wave + one L1-wave -> independent streams overlap.
// Iteration i: L0 computes step i (reads hbuf[0][p], x_i); L1 computes step
// i-1 (reads hbuf[1][p] + ys0[i-1]=hbuf[0][p]); both write buf p^1; 1 barrier.
__global__ __launch_bounds__(512, 1) void k2_gru(
        const f16* __restrict__ x,
        const float* __restrict__ Wih0, const float* __restrict__ Whh0,
        const float* __restrict__ bih0, const float* __restrict__ bhh0,
        const float* __restrict__ Wih1, const float* __restrict__ Whh1,
        const float* __restrict__ bih1, const float* __restrict__ bhh1,
        const float* __restrict__ W1, const float* __restrict__ b1,
        const float* __restrict__ W2, const float* __restrict__ b2,
        float* __restrict__ out) {
    __shared__ __align__(16) f16 hbuf[2][2][16 * 72];   // [layer][pingpong][row*72+col]
    int tid = threadIdx.x;
    int lane = tid & 63;
    int wv = __builtin_amdgcn_readfirstlane(tid >> 6);  // 0..7
    int L = wv >> 2;                                    // layer this wave owns
    int S = (wv & 3) * 16;                              // hidden strip
    int c = lane & 15, q = lane >> 4;
    int rowbase = blockIdx.x * 16;

    for (int k = tid; k < 2 * 2 * 16 * 72; k += 512) ((f16*)hbuf)[k] = (f16)0.f;

    auto ldw = [&](const float* W, int row0, int kcol) -> f16x8 {
        const float* p = W + (size_t)(row0 + c) * 64 + kcol + q * 8;
        f32x4 w0 = *(const f32x4*)p;
        f32x4 w1 = *(const f32x4*)(p + 4);
        f16x8 r;
        r[0] = (f16)w0[0]; r[1] = (f16)w0[1]; r[2] = (f16)w0[2]; r[3] = (f16)w0[3];
        r[4] = (f16)w1[0]; r[5] = (f16)w1[1]; r[6] = (f16)w1[2]; r[7] = (f16)w1[3];
        return r;
    };

    const float* Wih = L ? Wih1 : Wih0;
    const float* Whh = L ? Whh1 : Whh0;
    const float* bih = L ? bih1 : bih0;
    const float* bhh = L ? bhh1 : bhh0;

    f16x8 wih[3][2], whh[3][2];
#pragma unroll
    for (int g = 0; g < 3; g++)
#pragma unroll
        for (int kf = 0; kf < 2; kf++) {
            wih[g][kf] = ldw(Wih, g * 64 + S, kf * 32);
            whh[g][kf] = ldw(Whh, g * 64 + S, kf * 32);
        }

    float br = bih[S + c] + bhh[S + c];
    float bz = bih[64 + S + c] + bhh[64 + S + c];
    float bi = bih[128 + S + c];
    float bh = bhh[128 + S + c];
    f32x4 vbr = {br, br, br, br}, vbz = {bz, bz, bz, bz};
    f32x4 vbi = {bi, bi, bi, bi}, vbh = {bh, bh, bh, bh};

    f32x4 hc = {0.f, 0.f, 0.f, 0.f};

    auto ldx = [&](int t, int kf) -> f16x8 {
        return *(const f16x8*)(x + ((size_t)t * B_ + rowbase + c) * 64 + kf * 32 + q * 8);
    };

    __syncthreads();   // LDS zeros visible

    int p = 0;
    f16x8 xa0 = {}, xa1 = {}, xn0 = {}, xn1 = {};
    if (L == 0) { xa0 = ldx(0, 0); xa1 = ldx(0, 1); xn0 = xa0; xn1 = xa1; }

    for (int i = 0; i <= T_; i++) {
        f16x8 hh0, hh1, in0, in1;
        if (L == 0) {
            if (i + 1 < T_) { xn0 = ldx(i + 1, 0); xn1 = ldx(i + 1, 1); }
            hh0 = *(const f16x8*)&hbuf[0][p][c * 72 + q * 8];
            hh1 = *(const f16x8*)&hbuf[0][p][c * 72 + 32 + q * 8];
            in0 = xa0; in1 = xa1;
        } else {
            hh0 = *(const f16x8*)&hbuf[1][p][c * 72 + q * 8];
            hh1 = *(const f16x8*)&hbuf[1][p][c * 72 + 32 + q * 8];
            in0 = *(const f16x8*)&hbuf[0][p][c * 72 + q * 8];
            in1 = *(const f16x8*)&hbuf[0][p][c * 72 + 32 + q * 8];
        }
        bool active = L ? (i > 0) : (i < T_);
        if (active) {
            f32x4 r = vbr, z = vbz, in_ = vbi, hn = vbh;
            r = mfma16(hh0, whh[0][0], r); r = mfma16(hh1, whh[0][1], r);
            r = mfma16(in0, wih[0][0], r); r = mfma16(in1, wih[0][1], r);
            z = mfma16(hh0, whh[1][0], z); z = mfma16(hh1, whh[1][1], z);
            z = mfma16(in0, wih[1][0], z); z = mfma16(in1, wih[1][1], z);
            in_ = mfma16(in0, wih[2][0], in_); in_ = mfma16(in1, wih[2][1], in_);
            hn = mfma16(hh0, whh[2][0], hn); hn = mfma16(hh1, whh[2][1], hn);
#pragma unroll
            for (int rr = 0; rr < 4; rr++) {
                float rg = sigmoid_f(r[rr]);
                float zg = sigmoid_f(z[rr]);
                float ng = tanh_f(in_[rr] + rg * hn[rr]);
                hc[rr] = ng + zg * (hc[rr] - ng);
            }
        }
#pragma unroll
        for (int rr = 0; rr < 4; rr++)
            hbuf[L][p ^ 1][(q * 4 + rr) * 72 + S + c] = (f16)hc[rr];
        __syncthreads();
        p ^= 1;
        if (L == 0) { xa0 = xn0; xa1 = xn1; }
    }

    // ---- classifier: hid = relu(h1 @ W1^T + b1) by waves 0-3; logits by wave 0
    f16x8 ha0 = *(const f16x8*)&hbuf[1][p][c * 72 + q * 8];
    f16x8 ha1 = *(const f16x8*)&hbuf[1][p][c * 72 + 32 + q * 8];
    if (L == 0) {
        f16x8 w1f0 = ldw(W1, S, 0), w1f1 = ldw(W1, S, 32);
        float bw1 = b1[S + c];
        f32x4 hid = {bw1, bw1, bw1, bw1};
        hid = mfma16(ha0, w1f0, hid);
        hid = mfma16(ha1, w1f1, hid);
#pragma unroll
        for (int rr = 0; rr < 4; rr++) {
            float hv = fmaxf(hid[rr], 0.f);
            hbuf[0][p ^ 1][(q * 4 + rr) * 72 + S + c] = (f16)hv;
        }
    }
    __syncthreads();
    if (wv == 0) {
        f16x8 ga0 = *(const f16x8*)&hbuf[0][p ^ 1][c * 72 + q * 8];
        f16x8 ga1 = *(const f16x8*)&hbuf[0][p ^ 1][c * 72 + 32 + q * 8];
        f16x8 w2f0 = {}, w2f1 = {};
        float bo = 0.f;
        if (c < 8) {
            w2f0 = ldw(W2, 0, 0);
            w2f1 = ldw(W2, 0, 32);
            bo = b2[c];
        }
        f32x4 lg = {bo, bo, bo, bo};
        lg = mfma16(ga0, w2f0, lg);
        lg = mfma16(ga1, w2f1, lg);
        if (c < 8) {
#pragma unroll
            for (int rr = 0; rr < 4; rr++)
                out[(size_t)(rowbase + q * 4 + rr) * 8 + c] = lg[rr];
        }
    }
}

extern "C" void kernel_launch(void* const* d_in, const int* in_sizes, int n_in,
                              void* d_out, int out_size, void* d_ws, size_t ws_size,
                              hipStream_t stream) {
    const float* obs  = (const float*)d_in[0];
    const int*   act  = (const int*)d_in[1];
    const float* projW = (const float*)d_in[2];
    const float* projb = (const float*)d_in[3];
    const float* lng  = (const float*)d_in[4];
    const float* lnb  = (const float*)d_in[5];
    const float* Wih0 = (const float*)d_in[6];
    const float* Whh0 = (const float*)d_in[7];
    const float* bih0 = (const float*)d_in[8];
    const float* bhh0 = (const float*)d_in[9];
    const float* Wih1 = (const float*)d_in[10];
    const float* Whh1 = (const float*)d_in[11];
    const float* bih1 = (const float*)d_in[12];
    const float* bhh1 = (const float*)d_in[13];
    const float* W1   = (const float*)d_in[14];
    const float* b1   = (const float*)d_in[15];
    const float* W2   = (const float*)d_in[16];
    const float* b2   = (const float*)d_in[17];
    float* out = (float*)d_out;

    char* ws = (char*)d_ws;
    float* WT = (float*)ws;                          // 25344 B
    f16*   xw = (f16*)(ws + 32768);                  // 131072*64*2 = 16 MiB

    k0_transpose<<<25, 256, 0, stream>>>(projW, WT);
    k1_fused<<<NBT / 256, 256, 0, stream>>>(obs, act, WT, projb, lng, lnb, xw);
    k2_gru<<<B_ / 16, 512, 0, stream>>>(xw, Wih0, Whh0, bih0, bhh0,
                                        Wih1, Whh1, bih1, bhh1,
                                        W1, b1, W2, b2, out);
}

// Round 5
// 385.972 us; speedup vs baseline: 1.0231x; 1.0231x over previous
//
#include <hip/hip_runtime.h>

#define B_ 4096
#define T_ 32
#define A_ 4
#define OBS_ 115
#define H_ 64
#define IN_DIM_ 99
#define ACT_ 19
#define NBT (B_*T_)

typedef _Float16 f16;
typedef _Float16 f16x8 __attribute__((ext_vector_type(8)));
typedef float f32x4 __attribute__((ext_vector_type(4)));

static __device__ __forceinline__ float sigmoid_f(float x) {
    return __builtin_amdgcn_rcpf(1.f + __expf(-x));
}
static __device__ __forceinline__ float tanh_f(float x) {
    return 1.f - 2.f * __builtin_amdgcn_rcpf(1.f + __expf(2.f * x));
}
static __device__ __forceinline__ f32x4 mfma16(f16x8 a, f16x8 b, f32x4 c) {
    return __builtin_amdgcn_mfma_f32_16x16x32_f16(a, b, c, 0, 0, 0);
}

// ---- ONE fused kernel: features -> proj+LN -> 2-layer GRU -> classifier ----
// Grid 256 x 512 thr. Block owns batch rows [16*blk, 16*blk+16) for all T.
// LDS budget: fl 51200 + wtl 25344 + al 2048 + xls 73728 + hbuf 9216 = 161536 B.
__global__ __launch_bounds__(512, 1) void fused_all(
        const float* __restrict__ obs, const int* __restrict__ act,
        const float* __restrict__ projW, const float* __restrict__ pb,
        const float* __restrict__ lng, const float* __restrict__ lnb,
        const float* __restrict__ Wih0, const float* __restrict__ Whh0,
        const float* __restrict__ bih0, const float* __restrict__ bhh0,
        const float* __restrict__ Wih1, const float* __restrict__ Whh1,
        const float* __restrict__ bih1, const float* __restrict__ bhh1,
        const float* __restrict__ W1, const float* __restrict__ b1,
        const float* __restrict__ W2, const float* __restrict__ b2,
        float* __restrict__ out) {
    __shared__ float fl[512 * 25];                       // features
    __shared__ float wtl[IN_DIM_ * 64];                  // proj_W transposed
    __shared__ int al[512];                              // 4 actions packed/bt
    __shared__ __align__(16) f16 xls[32 * 16 * 72];      // x[t][row][h], pad 72
    __shared__ __align__(16) f16 hbuf[2][2][16 * 72];    // [layer][pp][row*72+c]

    int tid = threadIdx.x;
    int lane = tid & 63;
    int wv = __builtin_amdgcn_readfirstlane(tid >> 6);   // 0..7
    int c = lane & 15, q = lane >> 4;
    int rowbase = blockIdx.x * 16;

    // ---- GRU weight preamble (cold HBM latency hides under phase A/B) ----
    auto ldw = [&](const float* W, int row0, int kcol) -> f16x8 {
        const float* p = W + (size_t)(row0 + c) * 64 + kcol + q * 8;
        f32x4 w0 = *(const f32x4*)p;
        f32x4 w1 = *(const f32x4*)(p + 4);
        f16x8 r;
        r[0] = (f16)w0[0]; r[1] = (f16)w0[1]; r[2] = (f16)w0[2]; r[3] = (f16)w0[3];
        r[4] = (f16)w1[0]; r[5] = (f16)w1[1]; r[6] = (f16)w1[2]; r[7] = (f16)w1[3];
        return r;
    };
    int L = wv >> 2;                                     // GRU layer this wave owns
    int S = (wv & 3) * 16;                               // hidden strip
    const float* Wih = L ? Wih1 : Wih0;
    const float* Whh = L ? Whh1 : Whh0;
    const float* bih = L ? bih1 : bih0;
    const float* bhh = L ? bhh1 : bhh0;
    f16x8 wih[3][2], whh[3][2];
#pragma unroll
    for (int g = 0; g < 3; g++)
#pragma unroll
        for (int kf = 0; kf < 2; kf++) {
            wih[g][kf] = ldw(Wih, g * 64 + S, kf * 32);
            whh[g][kf] = ldw(Whh, g * 64 + S, kf * 32);
        }
    float br = bih[S + c] + bhh[S + c];
    float bz = bih[64 + S + c] + bhh[64 + S + c];
    float bi = bih[128 + S + c];
    float bh = bhh[128 + S + c];
    f32x4 vbr = {br, br, br, br}, vbz = {bz, bz, bz, bz};
    f32x4 vbi = {bi, bi, bi, bi}, vbh = {bh, bh, bh, bh};

    // ---- Phase A: feature extraction, thread per bt; stage wtl + hbuf ----
    {
        int n = blockIdx.x * 512 + tid;                  // global bt
        const float* o = obs + (size_t)n * (A_ * OBS_);
        float px[A_], py[A_];
#pragma unroll
        for (int a = 0; a < A_; a++) {
            float2 p2 = *(const float2*)&o[a * OBS_];
            px[a] = p2.x; py[a] = p2.y;
        }
        float2 bl = *(const float2*)&o[88];
        int t0 = tid & 31;
        float2 pbl = bl;
        if (t0 > 0) pbl = *(const float2*)&o[88 - A_ * OBS_];

        float cx = (px[0] + px[1] + px[2] + px[3]) * 0.25f;
        float cy = (py[0] + py[1] + py[2] + py[3]) * 0.25f;
        float sp = 0.f;
#pragma unroll
        for (int a = 0; a < A_; a++) { float dx = px[a] - cx, dy = py[a] - cy; sp += dx * dx + dy * dy; }
        sp = sqrtf(sp * 0.25f + 1e-6f);

        float crx[A_], cry[A_];
#pragma unroll
        for (int i = 0; i < A_; i++) {
            float best = 3.4e38f; int bj = 0;
#pragma unroll
            for (int j = 0; j < A_; j++) {
                if (j == i) continue;
                float dx = px[i] - px[j], dy = py[i] - py[j];
                float d2 = dx * dx + dy * dy;
                if (d2 < best) { best = d2; bj = j; }
            }
            crx[i] = px[bj] - px[i]; cry[i] = py[bj] - py[i];
        }

        float* f = &fl[tid * 25];
        f[0] = bl.x; f[1] = bl.y; f[2] = bl.x - pbl.x; f[3] = bl.y - pbl.y;
#pragma unroll
        for (int a = 0; a < A_; a++) { f[4 + 2 * a] = px[a]; f[5 + 2 * a] = py[a]; }
        f[12] = cx; f[13] = cy; f[14] = sp;
#pragma unroll
        for (int a = 0; a < A_; a++) { f[15 + 2 * a] = crx[a]; f[16 + 2 * a] = cry[a]; }

        int4 av = *(const int4*)&act[n * A_];
        al[tid] = av.x | (av.y << 8) | (av.z << 16) | (av.w << 24);

        for (int k = tid; k < IN_DIM_ * 64; k += 512) {
            int h = k / 64, i = k & 63;                  // read coalesced over k
            // store transposed: wtl[col*64+row] with projW[row=h? ...]
            // projW is [64][99]; we want wtl[i99*64 + h64] = projW[h64*99 + i99]
            int hh = k / IN_DIM_, ii = k - hh * IN_DIM_;
            (void)h; (void)i;
            wtl[ii * 64 + hh] = projW[k];
        }
        for (int k = tid; k < 2 * 2 * 16 * 72; k += 512) ((f16*)hbuf)[k] = (f16)0.f;
    }
    __syncthreads();

    // ---- Phase B: projection + LayerNorm + ReLU; wave handles 64 bt ----
    {
        float wc[23];
#pragma unroll
        for (int i = 0; i < 23; i++) wc[i] = wtl[i * 64 + lane];
        float pbv = pb[lane], g = lng[lane], bb = lnb[lane];

        for (int it = 0; it < 64; it++) {
            int lb = wv * 64 + it;                       // local bt in [0,512)
            int r = lb >> 5, t = lb & 31;
            const float* fp = &fl[lb * 25];
            float v = pbv;
#pragma unroll
            for (int i = 0; i < 23; i++) v += fp[i] * wc[i];
            int a4 = al[lb];
#pragma unroll
            for (int a = 0; a < A_; a++) {
                int ai = (a4 >> (8 * a)) & 0xFF;
                v += wtl[(23 + a * ACT_ + ai) * 64 + lane];
            }
            float s = v, ss = v * v;
#pragma unroll
            for (int m = 1; m < 64; m <<= 1) {
                s += __shfl_xor(s, m, 64);
                ss += __shfl_xor(ss, m, 64);
            }
            float mean = s * (1.f / 64.f);
            float var = ss * (1.f / 64.f) - mean * mean;
            float xn = (v - mean) * rsqrtf(var + 1e-5f) * g + bb;
            xn = fmaxf(xn, 0.f);
            xls[(t * 16 + r) * 72 + lane] = (f16)xn;
        }
    }
    __syncthreads();

    // ---- Phase C: layer-split GRU (R4 structure), x from LDS ----
    f32x4 hc = {0.f, 0.f, 0.f, 0.f};
    int p = 0;
    for (int i = 0; i <= T_; i++) {
        f16x8 hh0, hh1, in0, in1;
        if (L == 0) {
            hh0 = *(const f16x8*)&hbuf[0][p][c * 72 + q * 8];
            hh1 = *(const f16x8*)&hbuf[0][p][c * 72 + 32 + q * 8];
            int t = (i < T_) ? i : (T_ - 1);
            in0 = *(const f16x8*)&xls[(t * 16 + c) * 72 + q * 8];
            in1 = *(const f16x8*)&xls[(t * 16 + c) * 72 + 32 + q * 8];
        } else {
            hh0 = *(const f16x8*)&hbuf[1][p][c * 72 + q * 8];
            hh1 = *(const f16x8*)&hbuf[1][p][c * 72 + 32 + q * 8];
            in0 = *(const f16x8*)&hbuf[0][p][c * 72 + q * 8];
            in1 = *(const f16x8*)&hbuf[0][p][c * 72 + 32 + q * 8];
        }
        bool active = L ? (i > 0) : (i < T_);
        if (active) {
            f32x4 r = vbr, z = vbz, in_ = vbi, hn = vbh;
            r = mfma16(hh0, whh[0][0], r); r = mfma16(hh1, whh[0][1], r);
            r = mfma16(in0, wih[0][0], r); r = mfma16(in1, wih[0][1], r);
            z = mfma16(hh0, whh[1][0], z); z = mfma16(hh1, whh[1][1], z);
            z = mfma16(in0, wih[1][0], z); z = mfma16(in1, wih[1][1], z);
            in_ = mfma16(in0, wih[2][0], in_); in_ = mfma16(in1, wih[2][1], in_);
            hn = mfma16(hh0, whh[2][0], hn); hn = mfma16(hh1, whh[2][1], hn);
#pragma unroll
            for (int rr = 0; rr < 4; rr++) {
                float rg = sigmoid_f(r[rr]);
                float zg = sigmoid_f(z[rr]);
                float ng = tanh_f(in_[rr] + rg * hn[rr]);
                hc[rr] = ng + zg * (hc[rr] - ng);
            }
        }
#pragma unroll
        for (int rr = 0; rr < 4; rr++)
            hbuf[L][p ^ 1][(q * 4 + rr) * 72 + S + c] = (f16)hc[rr];
        __syncthreads();
        p ^= 1;
    }

    // ---- classifier ----
    f16x8 ha0 = *(const f16x8*)&hbuf[1][p][c * 72 + q * 8];
    f16x8 ha1 = *(const f16x8*)&hbuf[1][p][c * 72 + 32 + q * 8];
    if (L == 0) {
        f16x8 w1f0 = ldw(W1, S, 0), w1f1 = ldw(W1, S, 32);
        float bw1 = b1[S + c];
        f32x4 hid = {bw1, bw1, bw1, bw1};
        hid = mfma16(ha0, w1f0, hid);
        hid = mfma16(ha1, w1f1, hid);
#pragma unroll
        for (int rr = 0; rr < 4; rr++) {
            float hv = fmaxf(hid[rr], 0.f);
            hbuf[0][p ^ 1][(q * 4 + rr) * 72 + S + c] = (f16)hv;
        }
    }
    __syncthreads();
    if (wv == 0) {
        f16x8 ga0 = *(const f16x8*)&hbuf[0][p ^ 1][c * 72 + q * 8];
        f16x8 ga1 = *(const f16x8*)&hbuf[0][p ^ 1][c * 72 + 32 + q * 8];
        f16x8 w2f0 = {}, w2f1 = {};
        float bo = 0.f;
        if (c < 8) {
            w2f0 = ldw(W2, 0, 0);
            w2f1 = ldw(W2, 0, 32);
            bo = b2[c];
        }
        f32x4 lg = {bo, bo, bo, bo};
        lg = mfma16(ga0, w2f0, lg);
        lg = mfma16(ga1, w2f1, lg);
        if (c < 8) {
#pragma unroll
            for (int rr = 0; rr < 4; rr++)
                out[(size_t)(rowbase + q * 4 + rr) * 8 + c] = lg[rr];
        }
    }
}

extern "C" void kernel_launch(void* const* d_in, const int* in_sizes, int n_in,
                              void* d_out, int out_size, void* d_ws, size_t ws_size,
                              hipStream_t stream) {
    const float* obs  = (const float*)d_in[0];
    const int*   act  = (const int*)d_in[1];
    const float* projW = (const float*)d_in[2];
    const float* projb = (const float*)d_in[3];
    const float* lng  = (const float*)d_in[4];
    const float* lnb  = (const float*)d_in[5];
    const float* Wih0 = (const float*)d_in[6];
    const float* Whh0 = (const float*)d_in[7];
    const float* bih0 = (const float*)d_in[8];
    const float* bhh0 = (const float*)d_in[9];
    const float* Wih1 = (const float*)d_in[10];
    const float* Whh1 = (const float*)d_in[11];
    const float* bih1 = (const float*)d_in[12];
    const float* bhh1 = (const float*)d_in[13];
    const float* W1   = (const float*)d_in[14];
    const float* b1   = (const float*)d_in[15];
    const float* W2   = (const float*)d_in[16];
    const float* b2   = (const float*)d_in[17];
    float* out = (float*)d_out;

    fused_all<<<B_ / 16, 512, 0, stream>>>(obs, act, projW, projb, lng, lnb,
                                           Wih0, Whh0, bih0, bhh0,
                                           Wih1, Whh1, bih1, bhh1,
                                           W1, b1, W2, b2, out);
}